// Round 4
// baseline (551.625 us; speedup 1.0000x reference)
//
#include <hip/hip_runtime.h>
#include <hip/hip_bf16.h>
#include <cstdint>

// Problem constants
// B=128, P=168, M=8, HIDC=50, HIDR=50, HIDS=5, CK=6, SKIP=24, HW=24
// O = P*HIDC*CK = 50400, Kdim = P*M = 1344, L = 163, PT = 6
// Key identity: column o = hc*1008 + q contributes to res1[b][hc][t] with
// k = q/169, t = q%169, VALID iff t < 163 (intervals [169k,169k+163) disjoint)
// => the "sum over k" is a scatter from c's side; c never needs materializing.

typedef __attribute__((ext_vector_type(8))) short short8;   // 8 bf16 (4 VGPRs)
typedef __attribute__((ext_vector_type(4))) float f32x4;    // MFMA acc
typedef __attribute__((ext_vector_type(2))) float f32x2;    // packed fp32 (v_pk_fma_f32)

__device__ __forceinline__ unsigned short bf16rn(float f) {
    unsigned u = __float_as_uint(f);
    return (unsigned short)((u + 0x7FFFu + ((u >> 16) & 1u)) >> 16);
}
__device__ __forceinline__ unsigned pk2(float a, float b) {
    return ((unsigned)bf16rn(b) << 16) | (unsigned)bf16rn(a);
}
__device__ __forceinline__ uint4 pack8(float4 f0, float4 f1) {
    uint4 u;
    u.x = pk2(f0.x, f0.y); u.y = pk2(f0.z, f0.w);
    u.z = pk2(f1.x, f1.y); u.w = pk2(f1.z, f1.w);
    return u;
}
// fast activations: v_rcp_f32 instead of precise divide (serial-chain critical)
__device__ __forceinline__ float sigmf(float x) {
    return __builtin_amdgcn_rcpf(1.f + __expf(-x));
}
__device__ __forceinline__ float tanhf_(float x) {
    return 1.f - 2.f * __builtin_amdgcn_rcpf(__expf(2.f * x) + 1.f);
}

// ---------------------------------------------------------------------------
// K0: zero res1 (workspace is poisoned each iteration; atomics need 0-init)
// ---------------------------------------------------------------------------
__global__ __launch_bounds__(256)
void k0_zero(float* __restrict__ p) {
    int i = blockIdx.x * 256 + threadIdx.x;   // 260800 float4s = 1,043,200 floats
    if (i < 260800) reinterpret_cast<float4*>(p)[i] = (float4){0.f, 0.f, 0.f, 0.f};
}

// ---------------------------------------------------------------------------
// K1: GEMM M=128, N=50400, K=1344; epilogue scatters relu(acc+bias) straight
// into res1[b][hc][t] via atomicAdd (fp32, no bf16 c round-trip).
// Staging/MFMA structure unchanged from the verified version.
// ---------------------------------------------------------------------------
__global__ __launch_bounds__(256, 2)
void k1_conv_gemm(const float* __restrict__ x, const float* __restrict__ w,
                  const float* __restrict__ bias, float* __restrict__ res1) {
    __shared__ uint4 a_lds[8 * 129];  // A: 128 rows (b), pad->129
    __shared__ uint4 b_lds[8 * 113];  // B: 112 rows (o), pad->113
    const int tid  = threadIdx.x;
    const int n0   = blockIdx.x * 112;
    const int wave = tid >> 6, lane = tid & 63;
    const int quad = lane >> 4, m16 = lane & 15;

    f32x4 acc[2][7];
#pragma unroll
    for (int i = 0; i < 2; ++i)
#pragma unroll
        for (int j = 0; j < 7; ++j) acc[i][j] = (f32x4){0.f, 0.f, 0.f, 0.f};

    float4 pa[4][2];  // A prefetch regs
    float4 pb[4][2];  // B prefetch regs

    auto issue = [&](int kb) {
#pragma unroll
        for (int i = 0; i < 4; ++i) {
            int row = (tid >> 3) + 32 * i;
            const float* gp = x + row * 1344 + kb + (tid & 7) * 8;
            pa[i][0] = *reinterpret_cast<const float4*>(gp);
            pa[i][1] = *reinterpret_cast<const float4*>(gp + 4);
        }
#pragma unroll
        for (int i = 0; i < 4; ++i) {
            int idx = tid + 256 * i;
            if (idx < 896) {
                int row = idx >> 3;
                const float* gp = w + (size_t)(n0 + row) * 1344 + kb + (idx & 7) * 8;
                pb[i][0] = *reinterpret_cast<const float4*>(gp);
                pb[i][1] = *reinterpret_cast<const float4*>(gp + 4);
            }
        }
    };

    issue(0);
    for (int kb = 0; kb < 1344; kb += 64) {
#pragma unroll
        for (int i = 0; i < 4; ++i) {
            int idx = tid + 256 * i;
            int row = idx >> 3, ks = idx & 7;
            a_lds[ks * 129 + row] = pack8(pa[i][0], pa[i][1]);
        }
#pragma unroll
        for (int i = 0; i < 4; ++i) {
            int idx = tid + 256 * i;
            if (idx < 896) {
                int row = idx >> 3, ks = idx & 7;
                b_lds[ks * 113 + row] = pack8(pb[i][0], pb[i][1]);
            }
        }
        __syncthreads();
        if (kb + 64 < 1344) issue(kb + 64);
#pragma unroll
        for (int half = 0; half < 2; ++half) {
            const int kp = half * 4 + quad;
            short8 af[2], bfr[7];
#pragma unroll
            for (int rt = 0; rt < 2; ++rt)
                af[rt] = ((const short8*)a_lds)[kp * 129 + wave * 32 + rt * 16 + m16];
#pragma unroll
            for (int ct = 0; ct < 7; ++ct)
                bfr[ct] = ((const short8*)b_lds)[kp * 113 + ct * 16 + m16];
#pragma unroll
            for (int rt = 0; rt < 2; ++rt)
#pragma unroll
                for (int ct = 0; ct < 7; ++ct)
                    acc[rt][ct] = __builtin_amdgcn_mfma_f32_16x16x32_bf16(
                        af[rt], bfr[ct], acc[rt][ct], 0, 0, 0);
        }
        __syncthreads();
    }
    // epilogue: relu + scatter-add into res1[b][hc][t]  (b = grow)
#pragma unroll
    for (int ct = 0; ct < 7; ++ct) {
        int col = n0 + ct * 16 + m16;
        float bv = bias[col];
        unsigned uc = (unsigned)col;
        unsigned hc = uc / 1008u;
        unsigned q  = uc - hc * 1008u;
        unsigned kk = q / 169u;
        unsigned t  = q - kk * 169u;
        bool valid = (t < 163u);
        float* dst = res1 + hc * 163u + t;
#pragma unroll
        for (int rt = 0; rt < 2; ++rt) {
#pragma unroll
            for (int r = 0; r < 4; ++r) {
                int grow = wave * 32 + rt * 16 + quad * 4 + r;  // b
                float v = fmaxf(acc[rt][ct][r] + bv, 0.f);
                if (valid) atomicAdd(dst + (size_t)grow * 8150u, v);
            }
        }
    }
}

// ---------------------------------------------------------------------------
// K_PROJ: one block per b. Load res1[b] (coalesced) -> LDS, then input
// projections gi1[t][150], gi2[pt*24+sk][15] -> LDS -> coalesced global.
// ---------------------------------------------------------------------------
__global__ __launch_bounds__(384, 1)
void k_proj(const float* __restrict__ res1g,
            const float* __restrict__ g1_wih, const float* __restrict__ g1_bih,
            const float* __restrict__ gs_wih, const float* __restrict__ gs_bih,
            float* __restrict__ gi1g, float* __restrict__ gi2g) {
    __shared__ float rloc[50 * 164];   // [hc][t] pad 163->164
    __shared__ __align__(8) float gi1l[163 * 150];
    __shared__ __align__(8) float gi2l[144 * 15];

    const int b    = blockIdx.x;
    const int tid  = threadIdx.x;
    const int wave = tid >> 6, lane = tid & 63;

    // ---- load res1[b] into LDS (coalesced global read, strided LDS write) ----
    {
        const float* src = res1g + (size_t)b * 8150;
        for (int idx = tid; idx < 8150; idx += 384) {
            int hc = idx / 163, t = idx - hc * 163;
            rloc[hc * 164 + t] = src[idx];
        }
    }
    __syncthreads();

    // ---- input projections gi1 / gi2 into LDS ----
    {
        const int tB   = (wave >> 1) * 64 + lane;   // 0..191
        const int half = wave & 1;
        if (tB < 163) {
            float xcol[50];
#pragma unroll
            for (int j = 0; j < 50; ++j) xcol[j] = rloc[j * 164 + tB];

            const int c0 = __builtin_amdgcn_readfirstlane(half * 75);
            const float* wbase = g1_wih + c0 * 50;
            float* gdst = &gi1l[tB * 150 + c0];
            for (int cc = 0; cc < 75; ++cc) {
                const float* wp = wbase + cc * 50;
                float acc = g1_bih[c0 + cc];
#pragma unroll
                for (int j = 0; j < 50; ++j) acc += xcol[j] * wp[j];
                gdst[cc] = acc;
            }
            if (tB >= 19) {
                const int r2 = tB - 19;  // == pt*24 + sk
                const int d0 = __builtin_amdgcn_readfirstlane(half * 8);
                const int ncol = half ? 7 : 8;
                float* g2 = &gi2l[r2 * 15];
                for (int cc = 0; cc < ncol; ++cc) {
                    const float* wp = gs_wih + (d0 + cc) * 50;
                    float acc = gs_bih[d0 + cc];
#pragma unroll
                    for (int j = 0; j < 50; ++j) acc += xcol[j] * wp[j];
                    g2[d0 + cc] = acc;
                }
            }
        }
    }
    __syncthreads();

    // ---- coalesced copy-out ----
    {
        const float2* src = reinterpret_cast<const float2*>(gi1l);
        float2* dst = reinterpret_cast<float2*>(gi1g + (size_t)b * 24450);
        for (int i = tid; i < 12225; i += 384) dst[i] = src[i];
        const float2* s2 = reinterpret_cast<const float2*>(gi2l);
        float2* d2 = reinterpret_cast<float2*>(gi2g + (size_t)b * 2160);
        for (int i = tid; i < 1080; i += 384) d2[i] = s2[i];
    }
}

// ---------------------------------------------------------------------------
// K_GRU: GRU1 + GRU2 + final, one block per b, 64 threads (1 wave).
// Weights pinned in VGPRs; biases folded into the gi prefetch (off the
// serial chain); h broadcast via LDS (in-order per-wave DS, no barriers).
// ---------------------------------------------------------------------------
__global__ __launch_bounds__(64, 1)
void k_gru(const float* __restrict__ gi1g, const float* __restrict__ g1_whh,
           const float* __restrict__ g1_bhh,
           const float* __restrict__ gi2g, const float* __restrict__ gs_whh,
           const float* __restrict__ gs_bhh,
           const float* __restrict__ l1_w, const float* __restrict__ l1_b,
           const float* __restrict__ x, const float* __restrict__ hw_w,
           const float* __restrict__ hw_b, float* __restrict__ out) {
    __shared__ __align__(16) float hl[64];
    __shared__ float r1l[50];
    __shared__ float hsl[120];

    const int b = blockIdx.x;
    const int lane = threadIdx.x;
    const int lc = (lane < 50) ? lane : 49;

    // ---- pin recurrence weights in VGPRs ----
    f32x2 wr2[25], wz2[25], wn2[25];
    {
        const float* wrp = g1_whh + lc * 50;
        const float* wzp = g1_whh + (50 + lc) * 50;
        const float* wnp = g1_whh + (100 + lc) * 50;
#pragma unroll
        for (int j = 0; j < 25; ++j) {
            wr2[j] = *reinterpret_cast<const f32x2*>(wrp + 2 * j);
            wz2[j] = *reinterpret_cast<const f32x2*>(wzp + 2 * j);
            wn2[j] = *reinterpret_cast<const f32x2*>(wnp + 2 * j);
        }
#pragma unroll
        for (int j = 0; j < 25; ++j) {
            asm volatile("" : "+v"(wr2[j]));
            asm volatile("" : "+v"(wz2[j]));
            asm volatile("" : "+v"(wn2[j]));
        }
    }
    const float bhr = g1_bhh[lc], bhz = g1_bhh[50 + lc], bhn = g1_bhh[100 + lc];
    hl[lane] = 0.f;
    float hcur = 0.f;

    const float* gp = gi1g + (size_t)b * 24450;
    // biases folded at prefetch time (identical fp order to gir+bhr+... chain)
    float gir = gp[lc] + bhr, giz = gp[50 + lc] + bhz, gin = gp[100 + lc];
    for (int t = 0; t < 163; ++t) {
        float ngir = 0.f, ngiz = 0.f, ngin = 0.f;
        if (t < 162) {
            const float* gq = gp + 150;
            ngir = gq[lc] + bhr; ngiz = gq[50 + lc] + bhz; ngin = gq[100 + lc];
        }
        float4 h4[12];
#pragma unroll
        for (int j4 = 0; j4 < 12; ++j4)
            h4[j4] = *reinterpret_cast<const float4*>(&hl[4 * j4]);
        f32x2 ht; ht.x = hl[48]; ht.y = hl[49];
        f32x2 ar = {0.f, 0.f}, az = {0.f, 0.f}, an = {0.f, 0.f};
#pragma unroll
        for (int j4 = 0; j4 < 12; ++j4) {
            f32x2 h0; h0.x = h4[j4].x; h0.y = h4[j4].y;
            f32x2 h1; h1.x = h4[j4].z; h1.y = h4[j4].w;
            ar += wr2[2 * j4] * h0; ar += wr2[2 * j4 + 1] * h1;
            az += wz2[2 * j4] * h0; az += wz2[2 * j4 + 1] * h1;
            an += wn2[2 * j4] * h0; an += wn2[2 * j4 + 1] * h1;
        }
        ar += wr2[24] * ht; az += wz2[24] * ht; an += wn2[24] * ht;
        float rg = sigmf(gir + ar.x + ar.y);
        float zg = sigmf(giz + az.x + az.y);
        float ng = tanhf_(gin + rg * (bhn + an.x + an.y));
        hcur = fmaf(zg, hcur - ng, ng);   // == (1-zg)*ng + zg*hcur
        hl[lane] = hcur;                  // in-order DS: next iter sees this
        gir = ngir; giz = ngiz; gin = ngin;
        gp += 150;
    }
    if (lane < 50) r1l[lane] = hcur;

    // ---- GRU2: lanes 0..23, one sequence each (sk = lane), 6 steps ----
    if (lane < 24) {
        float h2[5] = {0.f, 0.f, 0.f, 0.f, 0.f};
        const float* g2base = gi2g + (size_t)b * 2160;
        for (int pt = 0; pt < 6; ++pt) {
            const float* g2 = g2base + (pt * 24 + lane) * 15;
            float gi[15];
#pragma unroll
            for (int i = 0; i < 15; ++i) gi[i] = g2[i];
            float gh[15];
#pragma unroll
            for (int i = 0; i < 15; ++i) {
                float s = gs_bhh[i];
#pragma unroll
                for (int j = 0; j < 5; ++j) s += gs_whh[i * 5 + j] * h2[j];
                gh[i] = s;
            }
#pragma unroll
            for (int u = 0; u < 5; ++u) {
                float rg = sigmf(gi[u] + gh[u]);
                float zg = sigmf(gi[5 + u] + gh[5 + u]);
                float ng = tanhf_(gi[10 + u] + rg * gh[10 + u]);
                h2[u] = (1.f - zg) * ng + zg * h2[u];
            }
        }
#pragma unroll
        for (int u = 0; u < 5; ++u) hsl[lane * 5 + u] = h2[u];
    }

    // ---- final linear + highway + sigmoid, lanes 0..7 ----
    if (lane < 8) {
        const int m = lane;
        float acc = l1_b[m];
        const float* wrow = l1_w + m * 170;
#pragma unroll
        for (int j = 0; j < 50; ++j) acc += r1l[j] * wrow[j];
#pragma unroll
        for (int j = 0; j < 120; ++j) acc += hsl[j] * wrow[50 + j];
        float z = hw_b[0];
        const float* xb = x + (size_t)b * 1344 + 144 * 8 + m;
#pragma unroll
        for (int wi = 0; wi < 24; ++wi) z += xb[wi * 8] * hw_w[wi];
        out[b * 8 + m] = __builtin_amdgcn_rcpf(1.f + __expf(-(acc + z)));
    }
}

// ---------------------------------------------------------------------------
extern "C" void kernel_launch(void* const* d_in, const int* in_sizes, int n_in,
                              void* d_out, int out_size, void* d_ws, size_t ws_size,
                              hipStream_t stream) {
    const float* x      = (const float*)d_in[0];
    const float* conv_w = (const float*)d_in[1];
    const float* conv_b = (const float*)d_in[2];
    const float* g1_wih = (const float*)d_in[3];
    const float* g1_whh = (const float*)d_in[4];
    const float* g1_bih = (const float*)d_in[5];
    const float* g1_bhh = (const float*)d_in[6];
    const float* gs_wih = (const float*)d_in[7];
    const float* gs_whh = (const float*)d_in[8];
    const float* gs_bih = (const float*)d_in[9];
    const float* gs_bhh = (const float*)d_in[10];
    const float* l1_w   = (const float*)d_in[11];
    const float* l1_b   = (const float*)d_in[12];
    const float* hw_w   = (const float*)d_in[13];
    const float* hw_b   = (const float*)d_in[14];
    float* out = (float*)d_out;

    char* ws = (char*)d_ws;
    float* res1g = (float*)ws;                      // 128*8150*4 =  4,172,800 B
    float* gi1g  = (float*)(ws + 4172800);          // 128*24450*4 = 12,518,400 B
    float* gi2g  = (float*)(ws + 16691200);         // 128*2160*4  =  1,105,920 B

    hipLaunchKernelGGL(k0_zero,      dim3(1019), dim3(256), 0, stream, res1g);
    hipLaunchKernelGGL(k1_conv_gemm, dim3(450),  dim3(256), 0, stream, x, conv_w, conv_b, res1g);
    hipLaunchKernelGGL(k_proj,       dim3(128),  dim3(384), 0, stream,
                       res1g, g1_wih, g1_bih, gs_wih, gs_bih, gi1g, gi2g);
    hipLaunchKernelGGL(k_gru,        dim3(128),  dim3(64),  0, stream,
                       gi1g, g1_whh, g1_bhh, gi2g, gs_whh, gs_bhh,
                       l1_w, l1_b, x, hw_w, hw_b, out);
}

// Round 5
// 531.943 us; speedup vs baseline: 1.0370x; 1.0370x over previous
//
#include <hip/hip_runtime.h>
#include <hip/hip_bf16.h>
#include <cstdint>

// Problem constants
// B=128, P=168, M=8, HIDC=50, HIDR=50, HIDS=5, CK=6, SKIP=24, HW=24
// O = P*HIDC*CK = 50400, Kdim = P*M = 1344, L = 163, PT = 6

typedef __attribute__((ext_vector_type(8))) short short8;   // 8 bf16 (4 VGPRs)
typedef __attribute__((ext_vector_type(4))) float f32x4;    // MFMA acc
typedef __attribute__((ext_vector_type(2))) float f32x2;    // packed fp32 (v_pk_fma_f32)

__device__ __forceinline__ unsigned short bf16rn(float f) {
    unsigned u = __float_as_uint(f);
    return (unsigned short)((u + 0x7FFFu + ((u >> 16) & 1u)) >> 16);
}
__device__ __forceinline__ unsigned pk2(float a, float b) {
    return ((unsigned)bf16rn(b) << 16) | (unsigned)bf16rn(a);
}
__device__ __forceinline__ uint4 pack8(float4 f0, float4 f1) {
    uint4 u;
    u.x = pk2(f0.x, f0.y); u.y = pk2(f0.z, f0.w);
    u.z = pk2(f1.x, f1.y); u.w = pk2(f1.z, f1.w);
    return u;
}
__device__ __forceinline__ float bf2f(unsigned short u) {
    return __uint_as_float((unsigned)u << 16);
}
// fast activations: v_rcp_f32 instead of precise divide (serial-chain critical)
__device__ __forceinline__ float sigmf(float x) {
    return __builtin_amdgcn_rcpf(1.f + __expf(-x));
}
__device__ __forceinline__ float tanhf_(float x) {
    return 1.f - 2.f * __builtin_amdgcn_rcpf(__expf(2.f * x) + 1.f);
}

// ---------------------------------------------------------------------------
// K1: c[b][o] = relu(xf @ wf^T + conv_b), stored bf16.  M=128, N=50400, K=1344.
// (reverted to the verified R2/R3 version: bf16 c output, no atomics)
// ---------------------------------------------------------------------------
__global__ __launch_bounds__(256, 2)
void k1_conv_gemm(const float* __restrict__ x, const float* __restrict__ w,
                  const float* __restrict__ bias, unsigned short* __restrict__ c) {
    __shared__ uint4 a_lds[8 * 129];  // A: 128 rows (b), pad->129
    __shared__ uint4 b_lds[8 * 113];  // B: 112 rows (o), pad->113
    const int tid  = threadIdx.x;
    const int n0   = blockIdx.x * 112;
    const int wave = tid >> 6, lane = tid & 63;
    const int quad = lane >> 4, m16 = lane & 15;

    f32x4 acc[2][7];
#pragma unroll
    for (int i = 0; i < 2; ++i)
#pragma unroll
        for (int j = 0; j < 7; ++j) acc[i][j] = (f32x4){0.f, 0.f, 0.f, 0.f};

    float4 pa[4][2];  // A prefetch regs
    float4 pb[4][2];  // B prefetch regs

    auto issue = [&](int kb) {
#pragma unroll
        for (int i = 0; i < 4; ++i) {
            int row = (tid >> 3) + 32 * i;
            const float* gp = x + row * 1344 + kb + (tid & 7) * 8;
            pa[i][0] = *reinterpret_cast<const float4*>(gp);
            pa[i][1] = *reinterpret_cast<const float4*>(gp + 4);
        }
#pragma unroll
        for (int i = 0; i < 4; ++i) {
            int idx = tid + 256 * i;
            if (idx < 896) {
                int row = idx >> 3;
                const float* gp = w + (size_t)(n0 + row) * 1344 + kb + (idx & 7) * 8;
                pb[i][0] = *reinterpret_cast<const float4*>(gp);
                pb[i][1] = *reinterpret_cast<const float4*>(gp + 4);
            }
        }
    };

    issue(0);
    for (int kb = 0; kb < 1344; kb += 64) {
#pragma unroll
        for (int i = 0; i < 4; ++i) {
            int idx = tid + 256 * i;
            int row = idx >> 3, ks = idx & 7;
            a_lds[ks * 129 + row] = pack8(pa[i][0], pa[i][1]);
        }
#pragma unroll
        for (int i = 0; i < 4; ++i) {
            int idx = tid + 256 * i;
            if (idx < 896) {
                int row = idx >> 3, ks = idx & 7;
                b_lds[ks * 113 + row] = pack8(pb[i][0], pb[i][1]);
            }
        }
        __syncthreads();
        if (kb + 64 < 1344) issue(kb + 64);
#pragma unroll
        for (int half = 0; half < 2; ++half) {
            const int kp = half * 4 + quad;
            short8 af[2], bfr[7];
#pragma unroll
            for (int rt = 0; rt < 2; ++rt)
                af[rt] = ((const short8*)a_lds)[kp * 129 + wave * 32 + rt * 16 + m16];
#pragma unroll
            for (int ct = 0; ct < 7; ++ct)
                bfr[ct] = ((const short8*)b_lds)[kp * 113 + ct * 16 + m16];
#pragma unroll
            for (int rt = 0; rt < 2; ++rt)
#pragma unroll
                for (int ct = 0; ct < 7; ++ct)
                    acc[rt][ct] = __builtin_amdgcn_mfma_f32_16x16x32_bf16(
                        af[rt], bfr[ct], acc[rt][ct], 0, 0, 0);
        }
        __syncthreads();
    }
#pragma unroll
    for (int ct = 0; ct < 7; ++ct) {
        int col = n0 + ct * 16 + m16;
        float bv = bias[col];
#pragma unroll
        for (int rt = 0; rt < 2; ++rt) {
#pragma unroll
            for (int r = 0; r < 4; ++r) {
                int grow = wave * 32 + rt * 16 + quad * 4 + r;
                float v = acc[rt][ct][r] + bv;
                v = fmaxf(v, 0.f);
                c[(size_t)grow * 50400 + col] = bf16rn(v);
            }
        }
    }
}

// ---------------------------------------------------------------------------
// K_FUSED2: everything after K1, one block per b (128 blocks, 256 threads).
// amdgpu_waves_per_eu(1,1): 4 waves/block = 1 wave/SIMD -> 512-VGPR budget,
// so the GRU's ~150 pinned weight regs CANNOT spill (R2's suspected defect),
// and gi1 stays in LDS so there is no global latency on the serial chain
// (R3's suspected defect).
//   Phase A (4 waves): rloc[hc][t] = sum_k c[b][...]
//   Phase B (4 waves, 6 wave-tasks): gi1[t][150], gi2[pt*24+sk][15] -> LDS
//   barrier; waves 1..3 return. Wave 0: GRU1 (163 steps, barrier-free,
//   h via in-order LDS, gi prefetched 1 step ahead from LDS), then GRU2,
//   then final linear + highway.
// ---------------------------------------------------------------------------
__attribute__((amdgpu_waves_per_eu(1, 1)))
__global__ __launch_bounds__(256, 1)
void k_fused2(const unsigned short* __restrict__ c,
              const float* __restrict__ g1_wih, const float* __restrict__ g1_whh,
              const float* __restrict__ g1_bih, const float* __restrict__ g1_bhh,
              const float* __restrict__ gs_wih, const float* __restrict__ gs_whh,
              const float* __restrict__ gs_bih, const float* __restrict__ gs_bhh,
              const float* __restrict__ l1_w, const float* __restrict__ l1_b,
              const float* __restrict__ x, const float* __restrict__ hw_w,
              const float* __restrict__ hw_b, float* __restrict__ out) {
    __shared__ float rloc[50 * 164];   // [hc][t] pad 163->164  (32.8 KB)
    __shared__ float gi1l[163 * 150];  // [t][150]              (97.8 KB)
    __shared__ float gi2l[144 * 15];   //                       ( 8.6 KB)
    __shared__ __align__(16) float hl[64];
    __shared__ float r1l[50];
    __shared__ float hsl[120];

    const int b    = blockIdx.x;
    const int tid  = threadIdx.x;
    const int wave = tid >> 6, lane = tid & 63;

    // ---- Phase A: diagonal-sum into rloc ----
    const unsigned short* cb = c + (size_t)b * 50400;
    for (int idx = tid; idx < 8150; idx += 256) {
        int hc = idx / 163, t = idx - hc * 163;
        int base = hc * 1008 + t;
        float s = 0.f;
#pragma unroll
        for (int k = 0; k < 6; ++k) s += bf2f(cb[base + 169 * k]);
        rloc[hc * 164 + t] = s;
    }
    __syncthreads();

    // ---- Phase B: input projections; 6 wave-tasks over 4 waves ----
    for (int task = wave; task < 6; task += 4) {
        const int tB   = (task >> 1) * 64 + lane;   // t block 0/64/128
        const int half = task & 1;                  // wave-uniform
        if (tB < 163) {
            float xcol[50];
#pragma unroll
            for (int j = 0; j < 50; ++j) xcol[j] = rloc[j * 164 + tB];

            const int c0 = __builtin_amdgcn_readfirstlane(half * 75);
            const float* wbase = g1_wih + c0 * 50;
            float* gdst = &gi1l[tB * 150 + c0];
            for (int cc = 0; cc < 75; ++cc) {
                const float* wp = wbase + cc * 50;
                float acc = g1_bih[c0 + cc];
#pragma unroll
                for (int j = 0; j < 50; ++j) acc += xcol[j] * wp[j];
                gdst[cc] = acc;
            }
            if (tB >= 19) {
                const int r2 = tB - 19;  // == pt*24 + sk
                const int d0 = __builtin_amdgcn_readfirstlane(half * 8);
                const int ncol = half ? 7 : 8;
                float* g2 = &gi2l[r2 * 15];
                for (int cc = 0; cc < ncol; ++cc) {
                    const float* wp = gs_wih + (d0 + cc) * 50;
                    float acc = gs_bih[d0 + cc];
#pragma unroll
                    for (int j = 0; j < 50; ++j) acc += xcol[j] * wp[j];
                    g2[d0 + cc] = acc;
                }
            }
        }
    }
    __syncthreads();
    if (wave != 0) return;   // wave 0 owns the serial tail; no barriers below

    // ---- GRU1: weights pinned in VGPRs (512 budget -> no spill) ----
    const int lc = (lane < 50) ? lane : 49;
    f32x2 wr2[25], wz2[25], wn2[25];
    {
        const float* wrp = g1_whh + lc * 50;          // rows 8B-aligned (200 B)
        const float* wzp = g1_whh + (50 + lc) * 50;
        const float* wnp = g1_whh + (100 + lc) * 50;
#pragma unroll
        for (int j = 0; j < 25; ++j) {
            wr2[j] = *reinterpret_cast<const f32x2*>(wrp + 2 * j);
            wz2[j] = *reinterpret_cast<const f32x2*>(wzp + 2 * j);
            wn2[j] = *reinterpret_cast<const f32x2*>(wnp + 2 * j);
        }
#pragma unroll
        for (int j = 0; j < 25; ++j) {
            asm volatile("" : "+v"(wr2[j]));
            asm volatile("" : "+v"(wz2[j]));
            asm volatile("" : "+v"(wn2[j]));
        }
    }
    const float bhr = g1_bhh[lc], bhz = g1_bhh[50 + lc], bhn = g1_bhh[100 + lc];
    hl[lane] = 0.f;
    float hcur = 0.f;

    // biases folded at prefetch (off the serial chain), gi from LDS
    float gir = gi1l[lc] + bhr, giz = gi1l[50 + lc] + bhz, gin = gi1l[100 + lc];
    int off = 150;
    for (int t = 0; t < 163; ++t) {
        float ngir = 0.f, ngiz = 0.f, ngin = 0.f;
        if (t < 162) {   // prefetch next step's gi from LDS (latency hidden)
            ngir = gi1l[off + lc] + bhr;
            ngiz = gi1l[off + 50 + lc] + bhz;
            ngin = gi1l[off + 100 + lc];
        }
        float4 h4[12];
#pragma unroll
        for (int j4 = 0; j4 < 12; ++j4)
            h4[j4] = *reinterpret_cast<const float4*>(&hl[4 * j4]);
        f32x2 ht; ht.x = hl[48]; ht.y = hl[49];
        f32x2 ar = {0.f, 0.f}, az = {0.f, 0.f}, an = {0.f, 0.f};
#pragma unroll
        for (int j4 = 0; j4 < 12; ++j4) {
            f32x2 h0; h0.x = h4[j4].x; h0.y = h4[j4].y;
            f32x2 h1; h1.x = h4[j4].z; h1.y = h4[j4].w;
            ar += wr2[2 * j4] * h0; ar += wr2[2 * j4 + 1] * h1;
            az += wz2[2 * j4] * h0; az += wz2[2 * j4 + 1] * h1;
            an += wn2[2 * j4] * h0; an += wn2[2 * j4 + 1] * h1;
        }
        ar += wr2[24] * ht; az += wz2[24] * ht; an += wn2[24] * ht;
        float rg = sigmf(gir + ar.x + ar.y);
        float zg = sigmf(giz + az.x + az.y);
        float ng = tanhf_(gin + rg * (bhn + an.x + an.y));
        hcur = fmaf(zg, hcur - ng, ng);   // == (1-zg)*ng + zg*hcur
        hl[lane] = hcur;                  // in-order DS: next iter sees this
        gir = ngir; giz = ngiz; gin = ngin;
        off += 150;
    }
    if (lane < 50) r1l[lane] = hcur;

    // ---- GRU2: lanes 0..23, one sequence each (sk = lane), 6 steps ----
    if (lane < 24) {
        float h2[5] = {0.f, 0.f, 0.f, 0.f, 0.f};
        for (int pt = 0; pt < 6; ++pt) {
            const float* g2 = &gi2l[(pt * 24 + lane) * 15];
            float gi[15];
#pragma unroll
            for (int i = 0; i < 15; ++i) gi[i] = g2[i];
            float gh[15];
#pragma unroll
            for (int i = 0; i < 15; ++i) {
                float s = gs_bhh[i];
#pragma unroll
                for (int j = 0; j < 5; ++j) s += gs_whh[i * 5 + j] * h2[j];
                gh[i] = s;
            }
#pragma unroll
            for (int u = 0; u < 5; ++u) {
                float rg = sigmf(gi[u] + gh[u]);
                float zg = sigmf(gi[5 + u] + gh[5 + u]);
                float ng = tanhf_(gi[10 + u] + rg * gh[10 + u]);
                h2[u] = (1.f - zg) * ng + zg * h2[u];
            }
        }
#pragma unroll
        for (int u = 0; u < 5; ++u) hsl[lane * 5 + u] = h2[u];
    }

    // ---- final linear + highway + sigmoid, lanes 0..7 ----
    if (lane < 8) {
        const int m = lane;
        float acc = l1_b[m];
        const float* wrow = l1_w + m * 170;
#pragma unroll
        for (int j = 0; j < 50; ++j) acc += r1l[j] * wrow[j];
#pragma unroll
        for (int j = 0; j < 120; ++j) acc += hsl[j] * wrow[50 + j];
        float z = hw_b[0];
        const float* xb = x + (size_t)b * 1344 + 144 * 8 + m;
#pragma unroll
        for (int wi = 0; wi < 24; ++wi) z += xb[wi * 8] * hw_w[wi];
        out[b * 8 + m] = __builtin_amdgcn_rcpf(1.f + __expf(-(acc + z)));
    }
}

// ---------------------------------------------------------------------------
extern "C" void kernel_launch(void* const* d_in, const int* in_sizes, int n_in,
                              void* d_out, int out_size, void* d_ws, size_t ws_size,
                              hipStream_t stream) {
    const float* x      = (const float*)d_in[0];
    const float* conv_w = (const float*)d_in[1];
    const float* conv_b = (const float*)d_in[2];
    const float* g1_wih = (const float*)d_in[3];
    const float* g1_whh = (const float*)d_in[4];
    const float* g1_bih = (const float*)d_in[5];
    const float* g1_bhh = (const float*)d_in[6];
    const float* gs_wih = (const float*)d_in[7];
    const float* gs_whh = (const float*)d_in[8];
    const float* gs_bih = (const float*)d_in[9];
    const float* gs_bhh = (const float*)d_in[10];
    const float* l1_w   = (const float*)d_in[11];
    const float* l1_b   = (const float*)d_in[12];
    const float* hw_w   = (const float*)d_in[13];
    const float* hw_b   = (const float*)d_in[14];
    float* out = (float*)d_out;

    unsigned short* c = (unsigned short*)d_ws;  // 12,902,400 B

    hipLaunchKernelGGL(k1_conv_gemm, dim3(450), dim3(256), 0, stream, x, conv_w, conv_b, c);
    hipLaunchKernelGGL(k_fused2,     dim3(128), dim3(256), 0, stream,
                       c, g1_wih, g1_whh, g1_bih, g1_bhh,
                       gs_wih, gs_whh, gs_bih, gs_bhh,
                       l1_w, l1_b, x, hw_w, hw_b, out);
}

// Round 6
// 522.541 us; speedup vs baseline: 1.0557x; 1.0180x over previous
//
#include <hip/hip_runtime.h>
#include <hip/hip_bf16.h>
#include <cstdint>

// Problem constants
// B=128, P=168, M=8, HIDC=50, HIDR=50, HIDS=5, CK=6, SKIP=24, HW=24
// O = P*HIDC*CK = 50400, Kdim = P*M = 1344, L = 163, PT = 6
// Diagonal identity: o = hc*1008 + k*168 + p, res1[b][hc][t] = sum_k relu-col
// at o = hc*1008 + 169k + t. K1 tiles N as (hc, t0): cols {hc*1008+169k+t0+i}
// so all 6 k-terms of an output live in one block's accumulators -> epilogue
// does relu+sum and writes fp32 res1 directly. No c tensor, no atomics.

typedef __attribute__((ext_vector_type(8))) short short8;   // 8 bf16 (4 VGPRs)
typedef __attribute__((ext_vector_type(4))) float f32x4;    // MFMA acc
typedef __attribute__((ext_vector_type(2))) float f32x2;    // packed fp32 (v_pk_fma_f32)

__device__ __forceinline__ unsigned short bf16rn(float f) {
    unsigned u = __float_as_uint(f);
    return (unsigned short)((u + 0x7FFFu + ((u >> 16) & 1u)) >> 16);
}
__device__ __forceinline__ unsigned pk2(float a, float b) {
    return ((unsigned)bf16rn(b) << 16) | (unsigned)bf16rn(a);
}
__device__ __forceinline__ uint4 pack8(float4 f0, float4 f1) {
    uint4 u;
    u.x = pk2(f0.x, f0.y); u.y = pk2(f0.z, f0.w);
    u.z = pk2(f1.x, f1.y); u.w = pk2(f1.z, f1.w);
    return u;
}
// fast activations: v_rcp_f32 instead of precise divide (serial-chain critical)
__device__ __forceinline__ float sigmf(float x) {
    return __builtin_amdgcn_rcpf(1.f + __expf(-x));
}
__device__ __forceinline__ float tanhf_(float x) {
    return 1.f - 2.f * __builtin_amdgcn_rcpf(__expf(2.f * x) + 1.f);
}

// ---------------------------------------------------------------------------
// K1: per-block GEMM tile M=128 x N=96 where the 96 cols are 6 k-chunks of 16
// t-values for one hc. Epilogue: res1[b][hc][t] = sum_ct relu(acc+bias).
// Staging/MFMA pipeline identical to the verified kernel (issue-after-barrier
// software pipeline, bf16 pack, 16x16x32 MFMA).
// Grid: 550 = 50 hc x 11 t-tiles (t0 = 16*tt, valid t < 163).
// ---------------------------------------------------------------------------
__global__ __launch_bounds__(256, 2)
void k1_conv_gemm(const float* __restrict__ x, const float* __restrict__ w,
                  const float* __restrict__ bias, float* __restrict__ res1) {
    __shared__ uint4 a_lds[8 * 129];  // A: 128 rows (b), pad->129
    __shared__ uint4 b_lds[8 * 97];   // B: 96 rows (6k x 16t), pad->97
    const int tid  = threadIdx.x;
    const int hc   = blockIdx.x / 11;
    const int tt   = blockIdx.x - hc * 11;
    const int t0   = tt * 16;
    const int wave = tid >> 6, lane = tid & 63;
    const int quad = lane >> 4, m16 = lane & 15;

    f32x4 acc[2][6];
#pragma unroll
    for (int i = 0; i < 2; ++i)
#pragma unroll
        for (int j = 0; j < 6; ++j) acc[i][j] = (f32x4){0.f, 0.f, 0.f, 0.f};

    float4 pa[4][2];  // A prefetch regs
    float4 pb[3][2];  // B prefetch regs (96 rows x 8 thr = 768 = 3*256 exact)

    auto issue = [&](int kb) {
#pragma unroll
        for (int i = 0; i < 4; ++i) {
            int row = (tid >> 3) + 32 * i;
            const float* gp = x + row * 1344 + kb + (tid & 7) * 8;
            pa[i][0] = *reinterpret_cast<const float4*>(gp);
            pa[i][1] = *reinterpret_cast<const float4*>(gp + 4);
        }
#pragma unroll
        for (int i = 0; i < 3; ++i) {
            int idx = tid + 256 * i;
            int rn  = idx >> 3;            // 0..95
            int k   = rn >> 4, ti = rn & 15;
            int t   = t0 + ti;
            int tc  = (t < 163) ? t : t0;  // clamp invalid tail rows (in-range)
            const float* gp = w + (size_t)(hc * 1008 + k * 169 + tc) * 1344
                                + kb + (idx & 7) * 8;
            pb[i][0] = *reinterpret_cast<const float4*>(gp);
            pb[i][1] = *reinterpret_cast<const float4*>(gp + 4);
        }
    };

    issue(0);
    for (int kb = 0; kb < 1344; kb += 64) {
#pragma unroll
        for (int i = 0; i < 4; ++i) {
            int idx = tid + 256 * i;
            int row = idx >> 3, ks = idx & 7;
            a_lds[ks * 129 + row] = pack8(pa[i][0], pa[i][1]);
        }
#pragma unroll
        for (int i = 0; i < 3; ++i) {
            int idx = tid + 256 * i;
            int row = idx >> 3, ks = idx & 7;
            b_lds[ks * 97 + row] = pack8(pb[i][0], pb[i][1]);
        }
        __syncthreads();
        if (kb + 64 < 1344) issue(kb + 64);
#pragma unroll
        for (int half = 0; half < 2; ++half) {
            const int kp = half * 4 + quad;
            short8 af[2], bfr[6];
#pragma unroll
            for (int rt = 0; rt < 2; ++rt)
                af[rt] = ((const short8*)a_lds)[kp * 129 + wave * 32 + rt * 16 + m16];
#pragma unroll
            for (int ct = 0; ct < 6; ++ct)
                bfr[ct] = ((const short8*)b_lds)[kp * 97 + ct * 16 + m16];
#pragma unroll
            for (int rt = 0; rt < 2; ++rt)
#pragma unroll
                for (int ct = 0; ct < 6; ++ct)
                    acc[rt][ct] = __builtin_amdgcn_mfma_f32_16x16x32_bf16(
                        af[rt], bfr[ct], acc[rt][ct], 0, 0, 0);
        }
        __syncthreads();
    }
    // epilogue: relu + k-sum + direct fp32 res1 write (no c round-trip)
    const int t = t0 + m16;
    if (t < 163) {
        float bv[6];
#pragma unroll
        for (int ct = 0; ct < 6; ++ct) bv[ct] = bias[hc * 1008 + ct * 169 + t];
#pragma unroll
        for (int rt = 0; rt < 2; ++rt) {
#pragma unroll
            for (int r = 0; r < 4; ++r) {
                int grow = wave * 32 + rt * 16 + quad * 4 + r;  // b
                float s = 0.f;
#pragma unroll
                for (int ct = 0; ct < 6; ++ct)
                    s += fmaxf(acc[rt][ct][r] + bv[ct], 0.f);
                res1[(size_t)grow * 8150 + hc * 163 + t] = s;
            }
        }
    }
}

// ---------------------------------------------------------------------------
// K_FUSED3: R2's best-measured tail structure (384 thr, 6 waves), with the
// scatter-gather phase A replaced by a coalesced res1[b] load (32.6 KB).
//   Phase A': load res1[b] -> rloc (coalesced), l1_w -> LDS.
//   Phase B: 6 waves, one (t-block, half) task each -> gi1/gi2 in LDS.
//   barrier; waves 1..5 return. Wave 0: GRU1 163 steps barrier-free
//   (weights pinned, gi prefetched 1 step ahead from LDS, biases folded),
//   then GRU2 (lanes 0..23), final linear+highway (lanes 0..7).
// ---------------------------------------------------------------------------
__global__ __launch_bounds__(384, 1)
void k_fused3(const float* __restrict__ res1g,
              const float* __restrict__ g1_wih, const float* __restrict__ g1_whh,
              const float* __restrict__ g1_bih, const float* __restrict__ g1_bhh,
              const float* __restrict__ gs_wih, const float* __restrict__ gs_whh,
              const float* __restrict__ gs_bih, const float* __restrict__ gs_bhh,
              const float* __restrict__ l1_w, const float* __restrict__ l1_b,
              const float* __restrict__ x, const float* __restrict__ hw_w,
              const float* __restrict__ hw_b, float* __restrict__ out) {
    __shared__ float rloc[50 * 164];   // [hc][t] pad 163->164  (32.8 KB)
    __shared__ float gi1l[163 * 150];  // [t][150]              (97.8 KB)
    __shared__ float gi2l[144 * 15];   //                       ( 8.6 KB)
    __shared__ float l1wl[8 * 170];
    __shared__ __align__(16) float hl[64];
    __shared__ float r1l[50];
    __shared__ float hsl[120];

    const int b    = blockIdx.x;
    const int tid  = threadIdx.x;
    const int wave = tid >> 6, lane = tid & 63;

    // ---- Phase A': coalesced res1[b] -> rloc ----
    {
        const float* src = res1g + (size_t)b * 8150;
        for (int idx = tid; idx < 8150; idx += 384) {
            int hc = idx / 163, t = idx - hc * 163;
            rloc[hc * 164 + t] = src[idx];
        }
        for (int idx = tid; idx < 1360; idx += 384) l1wl[idx] = l1_w[idx];
    }
    __syncthreads();

    // ---- Phase B: input projections; 6 waves, one task each ----
    {
        const int tB   = (wave >> 1) * 64 + lane;   // 0..191
        const int half = wave & 1;                  // wave-uniform
        if (tB < 163) {
            float xcol[50];
#pragma unroll
            for (int j = 0; j < 50; ++j) xcol[j] = rloc[j * 164 + tB];

            const int c0 = __builtin_amdgcn_readfirstlane(half * 75);
            const float* wbase = g1_wih + c0 * 50;
            float* gdst = &gi1l[tB * 150 + c0];
            for (int cc = 0; cc < 75; ++cc) {
                const float* wp = wbase + cc * 50;
                float acc = g1_bih[c0 + cc];
#pragma unroll
                for (int j = 0; j < 50; ++j) acc += xcol[j] * wp[j];
                gdst[cc] = acc;
            }
            if (tB >= 19) {
                const int r2 = tB - 19;  // == pt*24 + sk
                const int d0 = __builtin_amdgcn_readfirstlane(half * 8);
                const int ncol = half ? 7 : 8;
                float* g2 = &gi2l[r2 * 15];
                for (int cc = 0; cc < ncol; ++cc) {
                    const float* wp = gs_wih + (d0 + cc) * 50;
                    float acc = gs_bih[d0 + cc];
#pragma unroll
                    for (int j = 0; j < 50; ++j) acc += xcol[j] * wp[j];
                    g2[d0 + cc] = acc;
                }
            }
        }
    }
    __syncthreads();
    if (wave != 0) return;   // wave 0 owns the serial tail; no barriers below

    // ---- GRU1: weights pinned in VGPRs ----
    const int lc = (lane < 50) ? lane : 49;
    f32x2 wr2[25], wz2[25], wn2[25];
    {
        const float* wrp = g1_whh + lc * 50;          // rows 8B-aligned (200 B)
        const float* wzp = g1_whh + (50 + lc) * 50;
        const float* wnp = g1_whh + (100 + lc) * 50;
#pragma unroll
        for (int j = 0; j < 25; ++j) {
            wr2[j] = *reinterpret_cast<const f32x2*>(wrp + 2 * j);
            wz2[j] = *reinterpret_cast<const f32x2*>(wzp + 2 * j);
            wn2[j] = *reinterpret_cast<const f32x2*>(wnp + 2 * j);
        }
#pragma unroll
        for (int j = 0; j < 25; ++j) {
            asm volatile("" : "+v"(wr2[j]));
            asm volatile("" : "+v"(wz2[j]));
            asm volatile("" : "+v"(wn2[j]));
        }
    }
    const float bhr = g1_bhh[lc], bhz = g1_bhh[50 + lc], bhn = g1_bhh[100 + lc];
    hl[lane] = 0.f;
    float hcur = 0.f;

    // biases folded at prefetch (off the serial chain), gi from LDS
    float gir = gi1l[lc] + bhr, giz = gi1l[50 + lc] + bhz, gin = gi1l[100 + lc];
    int off = 150;
    for (int t = 0; t < 163; ++t) {
        float ngir = 0.f, ngiz = 0.f, ngin = 0.f;
        if (t < 162) {   // prefetch next step's gi from LDS (latency hidden)
            ngir = gi1l[off + lc] + bhr;
            ngiz = gi1l[off + 50 + lc] + bhz;
            ngin = gi1l[off + 100 + lc];
        }
        float4 h4[12];
#pragma unroll
        for (int j4 = 0; j4 < 12; ++j4)
            h4[j4] = *reinterpret_cast<const float4*>(&hl[4 * j4]);
        f32x2 ht; ht.x = hl[48]; ht.y = hl[49];
        f32x2 ar = {0.f, 0.f}, az = {0.f, 0.f}, an = {0.f, 0.f};
#pragma unroll
        for (int j4 = 0; j4 < 12; ++j4) {
            f32x2 h0; h0.x = h4[j4].x; h0.y = h4[j4].y;
            f32x2 h1; h1.x = h4[j4].z; h1.y = h4[j4].w;
            ar += wr2[2 * j4] * h0; ar += wr2[2 * j4 + 1] * h1;
            az += wz2[2 * j4] * h0; az += wz2[2 * j4 + 1] * h1;
            an += wn2[2 * j4] * h0; an += wn2[2 * j4 + 1] * h1;
        }
        ar += wr2[24] * ht; az += wz2[24] * ht; an += wn2[24] * ht;
        float rg = sigmf(gir + ar.x + ar.y);
        float zg = sigmf(giz + az.x + az.y);
        float ng = tanhf_(gin + rg * (bhn + an.x + an.y));
        hcur = fmaf(zg, hcur - ng, ng);   // == (1-zg)*ng + zg*hcur
        hl[lane] = hcur;                  // in-order DS: next iter sees this
        gir = ngir; giz = ngiz; gin = ngin;
        off += 150;
    }
    if (lane < 50) r1l[lane] = hcur;

    // ---- GRU2: lanes 0..23, one sequence each (sk = lane), 6 steps ----
    if (lane < 24) {
        float h2[5] = {0.f, 0.f, 0.f, 0.f, 0.f};
        for (int pt = 0; pt < 6; ++pt) {
            const float* g2 = &gi2l[(pt * 24 + lane) * 15];
            float gi[15];
#pragma unroll
            for (int i = 0; i < 15; ++i) gi[i] = g2[i];
            float gh[15];
#pragma unroll
            for (int i = 0; i < 15; ++i) {
                float s = gs_bhh[i];
#pragma unroll
                for (int j = 0; j < 5; ++j) s += gs_whh[i * 5 + j] * h2[j];
                gh[i] = s;
            }
#pragma unroll
            for (int u = 0; u < 5; ++u) {
                float rg = sigmf(gi[u] + gh[u]);
                float zg = sigmf(gi[5 + u] + gh[5 + u]);
                float ng = tanhf_(gi[10 + u] + rg * gh[10 + u]);
                h2[u] = (1.f - zg) * ng + zg * h2[u];
            }
        }
#pragma unroll
        for (int u = 0; u < 5; ++u) hsl[lane * 5 + u] = h2[u];
    }

    // ---- final linear + highway + sigmoid, lanes 0..7 ----
    if (lane < 8) {
        const int m = lane;
        float acc = l1_b[m];
        const float* wrow = &l1wl[m * 170];
#pragma unroll
        for (int j = 0; j < 50; ++j) acc += r1l[j] * wrow[j];
#pragma unroll
        for (int j = 0; j < 120; ++j) acc += hsl[j] * wrow[50 + j];
        float z = hw_b[0];
        const float* xb = x + (size_t)b * 1344 + 144 * 8 + m;
#pragma unroll
        for (int wi = 0; wi < 24; ++wi) z += xb[wi * 8] * hw_w[wi];
        out[b * 8 + m] = __builtin_amdgcn_rcpf(1.f + __expf(-(acc + z)));
    }
}

// ---------------------------------------------------------------------------
extern "C" void kernel_launch(void* const* d_in, const int* in_sizes, int n_in,
                              void* d_out, int out_size, void* d_ws, size_t ws_size,
                              hipStream_t stream) {
    const float* x      = (const float*)d_in[0];
    const float* conv_w = (const float*)d_in[1];
    const float* conv_b = (const float*)d_in[2];
    const float* g1_wih = (const float*)d_in[3];
    const float* g1_whh = (const float*)d_in[4];
    const float* g1_bih = (const float*)d_in[5];
    const float* g1_bhh = (const float*)d_in[6];
    const float* gs_wih = (const float*)d_in[7];
    const float* gs_whh = (const float*)d_in[8];
    const float* gs_bih = (const float*)d_in[9];
    const float* gs_bhh = (const float*)d_in[10];
    const float* l1_w   = (const float*)d_in[11];
    const float* l1_b   = (const float*)d_in[12];
    const float* hw_w   = (const float*)d_in[13];
    const float* hw_b   = (const float*)d_in[14];
    float* out = (float*)d_out;

    float* res1g = (float*)d_ws;   // 128*8150*4 = 4,172,800 B (fully overwritten)

    hipLaunchKernelGGL(k1_conv_gemm, dim3(550), dim3(256), 0, stream,
                       x, conv_w, conv_b, res1g);
    hipLaunchKernelGGL(k_fused3,     dim3(128), dim3(384), 0, stream,
                       res1g, g1_wih, g1_whh, g1_bih, g1_bhh,
                       gs_wih, gs_whh, gs_bih, gs_bhh,
                       l1_w, l1_b, x, hw_w, hw_b, out);
}

// Round 8
// 507.244 us; speedup vs baseline: 1.0875x; 1.0302x over previous
//
#include <hip/hip_runtime.h>
#include <hip/hip_bf16.h>
#include <cstdint>

// Problem constants
// B=128, P=168, M=8, HIDC=50, HIDR=50, HIDS=5, CK=6, SKIP=24, HW=24
// O = P*HIDC*CK = 50400, Kdim = P*M = 1344, L = 163, PT = 6

typedef __attribute__((ext_vector_type(8))) short short8;   // 8 bf16 (4 VGPRs)
typedef __attribute__((ext_vector_type(4))) float f32x4;    // MFMA acc
typedef __attribute__((ext_vector_type(2))) float f32x2;    // packed fp32 (v_pk_fma_f32)

__device__ __forceinline__ unsigned short bf16rn(float f) {
    unsigned u = __float_as_uint(f);
    return (unsigned short)((u + 0x7FFFu + ((u >> 16) & 1u)) >> 16);
}
// HW packed conversion: v_cvt_pk_bf16_f32 (RNE; validated in R7 pre-timing)
__device__ __forceinline__ unsigned pk2(float a, float b) {
    float2 f; f.x = a; f.y = b;
    __hip_bfloat162 h = __float22bfloat162_rn(f);
    union { __hip_bfloat162 h2; unsigned u; } cv;
    cv.h2 = h;
    return cv.u;
}
__device__ __forceinline__ uint4 pack8(float4 f0, float4 f1) {
    uint4 u;
    u.x = pk2(f0.x, f0.y); u.y = pk2(f0.z, f0.w);
    u.z = pk2(f1.x, f1.y); u.w = pk2(f1.z, f1.w);
    return u;
}
__device__ __forceinline__ float bf2f(unsigned short u) {
    return __uint_as_float((unsigned)u << 16);
}
// fast activations: v_rcp_f32 instead of precise divide (serial-chain critical)
__device__ __forceinline__ float sigmf(float x) {
    return __builtin_amdgcn_rcpf(1.f + __expf(-x));
}
__device__ __forceinline__ float tanhf_(float x) {
    return 1.f - 2.f * __builtin_amdgcn_rcpf(__expf(2.f * x) + 1.f);
}

// ---------------------------------------------------------------------------
// K1: c[b][o] = relu(xf @ wf^T + conv_b), stored bf16.  M=128, N=50400, K=1344.
// Verified R2 structure; only the staging bf16 pack now uses the HW
// v_cvt_pk_bf16_f32 (1 VALU op vs ~8 for the hand-rolled round).
// ---------------------------------------------------------------------------
__global__ __launch_bounds__(256, 2)
void k1_conv_gemm(const float* __restrict__ x, const float* __restrict__ w,
                  const float* __restrict__ bias, unsigned short* __restrict__ c) {
    __shared__ uint4 a_lds[8 * 129];  // A: 128 rows (b), pad->129
    __shared__ uint4 b_lds[8 * 113];  // B: 112 rows (o), pad->113
    const int tid  = threadIdx.x;
    const int n0   = blockIdx.x * 112;
    const int wave = tid >> 6, lane = tid & 63;
    const int quad = lane >> 4, m16 = lane & 15;

    f32x4 acc[2][7];
#pragma unroll
    for (int i = 0; i < 2; ++i)
#pragma unroll
        for (int j = 0; j < 7; ++j) acc[i][j] = (f32x4){0.f, 0.f, 0.f, 0.f};

    float4 pa[4][2];  // A prefetch regs
    float4 pb[4][2];  // B prefetch regs

    auto issue = [&](int kb) {
#pragma unroll
        for (int i = 0; i < 4; ++i) {
            int row = (tid >> 3) + 32 * i;
            const float* gp = x + row * 1344 + kb + (tid & 7) * 8;
            pa[i][0] = *reinterpret_cast<const float4*>(gp);
            pa[i][1] = *reinterpret_cast<const float4*>(gp + 4);
        }
#pragma unroll
        for (int i = 0; i < 4; ++i) {
            int idx = tid + 256 * i;
            if (idx < 896) {
                int row = idx >> 3;
                const float* gp = w + (size_t)(n0 + row) * 1344 + kb + (idx & 7) * 8;
                pb[i][0] = *reinterpret_cast<const float4*>(gp);
                pb[i][1] = *reinterpret_cast<const float4*>(gp + 4);
            }
        }
    };

    issue(0);
    for (int kb = 0; kb < 1344; kb += 64) {
#pragma unroll
        for (int i = 0; i < 4; ++i) {
            int idx = tid + 256 * i;
            int row = idx >> 3, ks = idx & 7;
            a_lds[ks * 129 + row] = pack8(pa[i][0], pa[i][1]);
        }
#pragma unroll
        for (int i = 0; i < 4; ++i) {
            int idx = tid + 256 * i;
            if (idx < 896) {
                int row = idx >> 3, ks = idx & 7;
                b_lds[ks * 113 + row] = pack8(pb[i][0], pb[i][1]);
            }
        }
        __syncthreads();
        if (kb + 64 < 1344) issue(kb + 64);
#pragma unroll
        for (int half = 0; half < 2; ++half) {
            const int kp = half * 4 + quad;
            short8 af[2], bfr[7];
#pragma unroll
            for (int rt = 0; rt < 2; ++rt)
                af[rt] = ((const short8*)a_lds)[kp * 129 + wave * 32 + rt * 16 + m16];
#pragma unroll
            for (int ct = 0; ct < 7; ++ct)
                bfr[ct] = ((const short8*)b_lds)[kp * 113 + ct * 16 + m16];
#pragma unroll
            for (int rt = 0; rt < 2; ++rt)
#pragma unroll
                for (int ct = 0; ct < 7; ++ct)
                    acc[rt][ct] = __builtin_amdgcn_mfma_f32_16x16x32_bf16(
                        af[rt], bfr[ct], acc[rt][ct], 0, 0, 0);
        }
        __syncthreads();
    }
#pragma unroll
    for (int ct = 0; ct < 7; ++ct) {
        int col = n0 + ct * 16 + m16;
        float bv = bias[col];
#pragma unroll
        for (int rt = 0; rt < 2; ++rt) {
#pragma unroll
            for (int r = 0; r < 4; ++r) {
                int grow = wave * 32 + rt * 16 + quad * 4 + r;
                float v = acc[rt][ct][r] + bv;
                v = fmaxf(v, 0.f);
                c[(size_t)grow * 50400 + col] = bf16rn(v);
            }
        }
    }
}

// ---------------------------------------------------------------------------
// K_FUSED: everything after K1, one block per b (128 blocks, 384 thr).
// Exact R2-verified structure (510.5 us):
//   Phase A (6 waves): rloc[hc][t] = sum_k c[b][...]
//   Phase B (6 waves): gi1[t][150], gi2[pt*24+sk][15] into LDS.
//   barrier; waves 1..5 return. Wave 0: GRU1 163 steps barrier-free
//   (f32x2 pinned weights, single in-order LDS h buffer), then GRU2,
//   then final linear+highway. Micro-opts proven in R3-R6: bias fold
//   into gi prefetch, fmaf h-update.
// ---------------------------------------------------------------------------
__global__ __launch_bounds__(384, 1)
void k_fused(const unsigned short* __restrict__ c,
             const float* __restrict__ g1_wih, const float* __restrict__ g1_whh,
             const float* __restrict__ g1_bih, const float* __restrict__ g1_bhh,
             const float* __restrict__ gs_wih, const float* __restrict__ gs_whh,
             const float* __restrict__ gs_bih, const float* __restrict__ gs_bhh,
             const float* __restrict__ l1_w, const float* __restrict__ l1_b,
             const float* __restrict__ x, const float* __restrict__ hw_w,
             const float* __restrict__ hw_b, float* __restrict__ out) {
    __shared__ float rloc[50 * 164];   // [hc][t] pad 163->164
    __shared__ float gi1l[163 * 150];  // [t][150]
    __shared__ float gi2l[144 * 15];   // [(pt*24+sk)][15]
    __shared__ float l1wl[8 * 170];
    __shared__ __align__(16) float hl[64];
    __shared__ float hsl[120];
    __shared__ float r1l[50];

    const int b    = blockIdx.x;
    const int tid  = threadIdx.x;
    const int wave = tid >> 6, lane = tid & 63;

    // ---- Phase A: diagonal-sum into rloc ----
    const unsigned short* cb = c + (size_t)b * 50400;
    for (int idx = tid; idx < 8150; idx += 384) {
        int hc = idx / 163, t = idx - hc * 163;
        int base = hc * 1008 + t;
        float s = 0.f;
#pragma unroll
        for (int k = 0; k < 6; ++k) s += bf2f(cb[base + 169 * k]);
        rloc[hc * 164 + t] = s;
    }
    for (int idx = tid; idx < 1360; idx += 384) l1wl[idx] = l1_w[idx];
    __syncthreads();

    // ---- Phase B: input projections gi1 / gi2 into LDS ----
    {
        const int tB   = (wave >> 1) * 64 + lane;   // 0..191
        const int half = wave & 1;
        if (tB < 163) {
            float xcol[50];
#pragma unroll
            for (int j = 0; j < 50; ++j) xcol[j] = rloc[j * 164 + tB];

            const int c0 = __builtin_amdgcn_readfirstlane(half * 75);
            const float* wbase = g1_wih + c0 * 50;
            float* gdst = &gi1l[tB * 150 + c0];
            for (int cc = 0; cc < 75; ++cc) {
                const float* wp = wbase + cc * 50;
                float acc = g1_bih[c0 + cc];
#pragma unroll
                for (int j = 0; j < 50; ++j) acc += xcol[j] * wp[j];
                gdst[cc] = acc;
            }
            if (tB >= 19) {
                const int r2 = tB - 19;  // == pt*24 + sk
                const int d0 = __builtin_amdgcn_readfirstlane(half * 8);
                const int ncol = half ? 7 : 8;
                float* g2 = &gi2l[r2 * 15];
                for (int cc = 0; cc < ncol; ++cc) {
                    const float* wp = gs_wih + (d0 + cc) * 50;
                    float acc = gs_bih[d0 + cc];
#pragma unroll
                    for (int j = 0; j < 50; ++j) acc += xcol[j] * wp[j];
                    g2[d0 + cc] = acc;
                }
            }
        }
    }
    __syncthreads();
    if (wave != 0) return;   // waves 1..5 done; no barriers below

    // ---- GRU1: single wave, weights pinned in VGPRs (f32x2, R2-proven) ----
    const int lc = (lane < 50) ? lane : 49;
    f32x2 wr2[25], wz2[25], wn2[25];
    {
        const float* wrp = g1_whh + lc * 50;          // rows 8B-aligned (200 B)
        const float* wzp = g1_whh + (50 + lc) * 50;
        const float* wnp = g1_whh + (100 + lc) * 50;
#pragma unroll
        for (int j = 0; j < 25; ++j) {
            wr2[j] = *reinterpret_cast<const f32x2*>(wrp + 2 * j);
            wz2[j] = *reinterpret_cast<const f32x2*>(wzp + 2 * j);
            wn2[j] = *reinterpret_cast<const f32x2*>(wnp + 2 * j);
        }
#pragma unroll
        for (int j = 0; j < 25; ++j) {  // pin into VGPRs (defeat remat/spill)
            asm volatile("" : "+v"(wr2[j]));
            asm volatile("" : "+v"(wz2[j]));
            asm volatile("" : "+v"(wn2[j]));
        }
    }
    const float bhr = g1_bhh[lc], bhz = g1_bhh[50 + lc], bhn = g1_bhh[100 + lc];
    hl[lane] = 0.f;
    float hcur = 0.f;
    // biases folded at prefetch (same fp association as (gir+bhr)+...)
    float gir = gi1l[lc] + bhr, giz = gi1l[50 + lc] + bhz, gin = gi1l[100 + lc];
    int off = 150;
    for (int t = 0; t < 163; ++t) {
        float ngir = 0.f, ngiz = 0.f, ngin = 0.f;
        if (t < 162) {   // prefetch next step's gi from LDS
            ngir = gi1l[off + lc] + bhr;
            ngiz = gi1l[off + 50 + lc] + bhz;
            ngin = gi1l[off + 100 + lc];
        }
        float4 h4[12];
#pragma unroll
        for (int j4 = 0; j4 < 12; ++j4)
            h4[j4] = *reinterpret_cast<const float4*>(&hl[4 * j4]);
        f32x2 ht; ht.x = hl[48]; ht.y = hl[49];
        f32x2 ar = {0.f, 0.f}, az = {0.f, 0.f}, an = {0.f, 0.f};
#pragma unroll
        for (int j4 = 0; j4 < 12; ++j4) {
            f32x2 h0; h0.x = h4[j4].x; h0.y = h4[j4].y;
            f32x2 h1; h1.x = h4[j4].z; h1.y = h4[j4].w;
            ar += wr2[2 * j4] * h0; ar += wr2[2 * j4 + 1] * h1;
            az += wz2[2 * j4] * h0; az += wz2[2 * j4 + 1] * h1;
            an += wn2[2 * j4] * h0; an += wn2[2 * j4 + 1] * h1;
        }
        ar += wr2[24] * ht; az += wz2[24] * ht; an += wn2[24] * ht;
        float rg = sigmf(gir + ar.x + ar.y);
        float zg = sigmf(giz + az.x + az.y);
        float ng = tanhf_(gin + rg * (bhn + an.x + an.y));
        hcur = fmaf(zg, hcur - ng, ng);   // == (1-zg)*ng + zg*hcur
        hl[lane] = hcur;                  // in-order DS: next iter sees this
        gir = ngir; giz = ngiz; gin = ngin;
        off += 150;
    }
    if (lane < 50) r1l[lane] = hcur;

    // ---- GRU2: lanes 0..23, one sequence each (sk = lane), 6 steps ----
    if (lane < 24) {
        float h2[5] = {0.f, 0.f, 0.f, 0.f, 0.f};
        for (int pt = 0; pt < 6; ++pt) {
            const float* gp = &gi2l[(pt * 24 + lane) * 15];
            float gi[15];
#pragma unroll
            for (int i = 0; i < 15; ++i) gi[i] = gp[i];
            float gh[15];
#pragma unroll
            for (int i = 0; i < 15; ++i) {
                float s = gs_bhh[i];
#pragma unroll
                for (int j = 0; j < 5; ++j) s += gs_whh[i * 5 + j] * h2[j];
                gh[i] = s;
            }
#pragma unroll
            for (int u = 0; u < 5; ++u) {
                float rg = sigmf(gi[u] + gh[u]);
                float zg = sigmf(gi[5 + u] + gh[5 + u]);
                float ng = tanhf_(gi[10 + u] + rg * gh[10 + u]);
                h2[u] = (1.f - zg) * ng + zg * h2[u];
            }
        }
#pragma unroll
        for (int u = 0; u < 5; ++u) hsl[lane * 5 + u] = h2[u];
    }

    // ---- final linear + highway + sigmoid, lanes 0..7 ----
    if (lane < 8) {
        const int m = lane;
        float acc = l1_b[m];
        const float* wrow = &l1wl[m * 170];
#pragma unroll
        for (int j = 0; j < 50; ++j) acc += r1l[j] * wrow[j];
#pragma unroll
        for (int j = 0; j < 120; ++j) acc += hsl[j] * wrow[50 + j];
        float z = hw_b[0];
        const float* xb = x + (size_t)b * 1344 + 144 * 8 + m;
#pragma unroll
        for (int wi = 0; wi < 24; ++wi) z += xb[wi * 8] * hw_w[wi];
        out[b * 8 + m] = __builtin_amdgcn_rcpf(1.f + __expf(-(acc + z)));
    }
}

// ---------------------------------------------------------------------------
extern "C" void kernel_launch(void* const* d_in, const int* in_sizes, int n_in,
                              void* d_out, int out_size, void* d_ws, size_t ws_size,
                              hipStream_t stream) {
    const float* x      = (const float*)d_in[0];
    const float* conv_w = (const float*)d_in[1];
    const float* conv_b = (const float*)d_in[2];
    const float* g1_wih = (const float*)d_in[3];
    const float* g1_whh = (const float*)d_in[4];
    const float* g1_bih = (const float*)d_in[5];
    const float* g1_bhh = (const float*)d_in[6];
    const float* gs_wih = (const float*)d_in[7];
    const float* gs_whh = (const float*)d_in[8];
    const float* gs_bih = (const float*)d_in[9];
    const float* gs_bhh = (const float*)d_in[10];
    const float* l1_w   = (const float*)d_in[11];
    const float* l1_b   = (const float*)d_in[12];
    const float* hw_w   = (const float*)d_in[13];
    const float* hw_b   = (const float*)d_in[14];
    float* out = (float*)d_out;

    unsigned short* c = (unsigned short*)d_ws;  // 12,902,400 B

    hipLaunchKernelGGL(k1_conv_gemm, dim3(450), dim3(256), 0, stream, x, conv_w, conv_b, c);
    hipLaunchKernelGGL(k_fused,      dim3(128), dim3(384), 0, stream,
                       c, g1_wih, g1_whh, g1_bih, g1_bhh,
                       gs_wih, gs_whh, gs_bih, gs_bhh,
                       l1_w, l1_b, x, hw_w, hw_b, out);
}